// Round 7
// baseline (358.737 us; speedup 1.0000x reference)
//
#include <hip/hip_runtime.h>

#define L_TOT 65536

// ws float offsets (mod_kernel outputs only)
#define WS_UG   0        // [4][128][8]
#define WS_VG   4096     // [4][128][8]
#define WS_A    8192     // [4][128]
#define WS_GB1  8704     // [4][128]
#define WS_CGP  32768    // uint[4][64][64]: packed bf16 pairs of Cg

typedef __attribute__((ext_vector_type(8))) short short8;
typedef __attribute__((ext_vector_type(4))) float f32x4;

__device__ __forceinline__ unsigned bf16rne(float f) {
    unsigned u = __builtin_bit_cast(unsigned, f);
    return (u + 0x7fffu + ((u >> 16) & 1u)) >> 16;
}

#define DPP_ROW(CT) \
    "v_add_f32_dpp %0, %0, %0 " CT "\n\t" \
    "v_add_f32_dpp %1, %1, %1 " CT "\n\t" \
    "v_add_f32_dpp %2, %2, %2 " CT "\n\t" \
    "v_add_f32_dpp %3, %3, %3 " CT "\n\t" \
    "v_add_f32_dpp %4, %4, %4 " CT "\n\t" \
    "v_add_f32_dpp %5, %5, %5 " CT "\n\t" \
    "v_add_f32_dpp %6, %6, %6 " CT "\n\t" \
    "v_add_f32_dpp %7, %7, %7 " CT "\n\t"

__global__ __launch_bounds__(128) void mod_kernel(
    const float* __restrict__ g,
    const float* __restrict__ U_base, const float* __restrict__ V_base,
    const float* __restrict__ a_base, const float* __restrict__ out_proj_w,
    const float* __restrict__ mod_uv_w, const float* __restrict__ mod_uv_b,
    const float* __restrict__ mod_a_w, const float* __restrict__ mod_a_b,
    const float* __restrict__ mod_B_w, const float* __restrict__ mod_B_b,
    const float* __restrict__ mod_C_w, const float* __restrict__ mod_C_b,
    float* __restrict__ ws)
{
    __shared__ float gsh[64];
    __shared__ float uvs[16];
    __shared__ float gCs[64];
    const int b = blockIdx.x, tid = threadIdx.x;
    if (tid < 64) gsh[tid] = g[b * 64 + tid];
    __syncthreads();
    if (tid < 16) {
        float s = mod_uv_b[tid];
        for (int d = 0; d < 64; ++d) s += mod_uv_w[tid * 64 + d] * gsh[d];
        uvs[tid] = fminf(0.5f, fmaxf(-0.5f, s));
    }
    float ga_v, gB_v;
    {
        float s = mod_a_b[tid];
        for (int d = 0; d < 64; ++d) s += mod_a_w[tid * 64 + d] * gsh[d];
        ga_v = fminf(2.0f, fmaxf(-2.0f, s));
    }
    {
        float s = mod_B_b[tid];
        for (int d = 0; d < 64; ++d) s += mod_B_w[tid * 64 + d] * gsh[d];
        gB_v = 1.0f + fminf(1.0f, fmaxf(-1.0f, s));
    }
    if (tid < 64) {
        float s = mod_C_b[tid];
        for (int d = 0; d < 64; ++d) s += mod_C_w[tid * 64 + d] * gsh[d];
        gCs[tid] = 1.0f + fminf(0.5f, fmaxf(-0.5f, s));
    }
    __syncthreads();
    for (int idx = tid; idx < 1024; idx += 128) {
        int m = idx >> 3, r = idx & 7;
        ws[WS_UG + (b * 128 + m) * 8 + r] = U_base[m * 8 + r] * (1.0f + uvs[r]);
        ws[WS_VG + (b * 128 + m) * 8 + r] = V_base[m * 8 + r] * (1.0f + uvs[8 + r]);
    }
    ws[WS_A   + b * 128 + tid] = a_base[tid] + ga_v;
    ws[WS_GB1 + b * 128 + tid] = gB_v;
    unsigned* CgP = (unsigned*)(ws + WS_CGP);
    for (int idx = tid; idx < 4096; idx += 128) {
        int c = idx >> 6, j = idx & 63;
        float s = gCs[c];
        float c0 = out_proj_w[c * 128 + 2 * j]     * s;
        float c1 = out_proj_w[c * 128 + 2 * j + 1] * s;
        CgP[(b * 64 + c) * 64 + j] = bf16rne(c0) | (bf16rne(c1) << 16);
    }
}

// Fused: per (b,chunk) block, 5 waves.
// wave0: recurrence (pure VALU+LDS). waves1-4: x_proj GEMM into xp dbuf.
// waves1-2 also: y = clip(Cg*H16) MFMA + stores, 1-seg lag.
// 33 intervals (k=-1..31), one __syncthreads per interval.
__global__ __launch_bounds__(320) void fused_kernel(
    const float* __restrict__ x, const float* __restrict__ W,
    const float* __restrict__ bias, const float* __restrict__ ws,
    const unsigned* __restrict__ CgP, const float* __restrict__ h0,
    float* __restrict__ out)
{
    __shared__ float Wsh[128 * 65];                 // 33.3 KB
    __shared__ float xp[2][16 * 130];               // 16.6 KB
    __shared__ __align__(16) unsigned Hs[2][16 * 68]; // 8.7 KB

    const int tid = threadIdx.x;
    const int lane = tid & 63;
    const int wid = tid >> 6;
    const int bb = blockIdx.x >> 7, kchunk = blockIdx.x & 127;
    const size_t l0chunk = (size_t)kchunk * 512;

    // ---- prologue: stage W (all threads) ----
    for (int u = tid; u < 8192; u += 320)
        Wsh[(u >> 6) * 65 + (u & 63)] = W[u];

    // ---- per-role parameter loads (global only; no LDS dependence) ----
    // scan params (wave 0)
    float Vg0[8], Vg1[8], Ug0[8], Ug1[8], a0 = 0.f, a1 = 0.f, ha = 0.f, hb = 0.f;
    const int m0 = 2 * lane;
    if (wid == 0) {
        const float* vg = ws + WS_VG + (bb * 128 + m0) * 8;
        const float* ug = ws + WS_UG + (bb * 128 + m0) * 8;
        #pragma unroll
        for (int r = 0; r < 8; ++r) {
            Vg0[r] = vg[r]; Vg1[r] = vg[8 + r];
            Ug0[r] = ug[r]; Ug1[r] = ug[8 + r];
        }
        a0 = ws[WS_A + bb * 128 + m0];
        a1 = ws[WS_A + bb * 128 + m0 + 1];
        ha = h0[m0]; hb = h0[m0 + 1];
    }
    // y params (waves 1,2): Cg A-fragments for 2 c-tiles each
    short8 Af[2][4];
    float* ob[2];
    const int row16 = lane & 15, grp = lane >> 4;
    if (wid == 1 || wid == 2) {
        #pragma unroll
        for (int cti = 0; cti < 2; ++cti) {
            int ct = (wid - 1) * 2 + cti;
            #pragma unroll
            for (int kc = 0; kc < 4; ++kc) {
                const unsigned* p = CgP + (bb * 64 + ct * 16 + row16) * 64 + kc * 16 + grp * 4;
                Af[cti][kc] = __builtin_bit_cast(short8, *(const uint4*)p);
            }
            ob[cti] = out + (size_t)(bb * 64 + ct * 16 + grp * 4) * L_TOT + l0chunk + row16;
        }
    }
    // GEMM params (waves 1-4)
    const int t_g = tid - 64;          // 0..255 for wid>=1
    const int mo = (t_g >> 1) & 127, lq = t_g & 1;
    float gb1s = 0.f, biass = 0.f;
    if (wid >= 1) {
        gb1s = ws[WS_GB1 + bb * 128 + mo];
        biass = bias[mo];
    }
    __syncthreads();   // Wsh ready

    for (int k = -1; k <= 31; ++k) {
        // ---------- waves 1-4: compute x_proj for seg s=k+1 ----------
        if (wid >= 1 && k <= 30) {
            const int s = k + 1;
            float* xpd = xp[s & 1];
            const float* xg = x + (size_t)(bb * 64) * L_TOT + l0chunk + s * 16 + lq * 8;
            const float* Wr = Wsh + mo * 65;
            float acc[8];
            #pragma unroll
            for (int j = 0; j < 8; ++j) acc[j] = 0.0f;
            #pragma unroll 4
            for (int c = 0; c < 64; ++c) {
                float w = Wr[c];
                float4 xa = *(const float4*)(xg + (size_t)c * L_TOT);
                float4 xb = *(const float4*)(xg + (size_t)c * L_TOT + 4);
                acc[0] = fmaf(w, xa.x, acc[0]);
                acc[1] = fmaf(w, xa.y, acc[1]);
                acc[2] = fmaf(w, xa.z, acc[2]);
                acc[3] = fmaf(w, xa.w, acc[3]);
                acc[4] = fmaf(w, xb.x, acc[4]);
                acc[5] = fmaf(w, xb.y, acc[5]);
                acc[6] = fmaf(w, xb.z, acc[6]);
                acc[7] = fmaf(w, xb.w, acc[7]);
            }
            #pragma unroll
            for (int j = 0; j < 8; ++j)
                xpd[(lq * 8 + j) * 130 + mo] = (acc[j] + biass) * gb1s;
        }
        // ---------- waves 1,2: y for seg k-1 ----------
        if ((wid == 1 || wid == 2) && k >= 1) {
            const int s = k - 1;
            const unsigned* Hp = Hs[s & 1];
            short8 Bf[4];
            #pragma unroll
            for (int kc = 0; kc < 4; ++kc)
                Bf[kc] = __builtin_bit_cast(short8,
                    *(const uint4*)&Hp[row16 * 68 + kc * 16 + grp * 4]);
            #pragma unroll
            for (int cti = 0; cti < 2; ++cti) {
                f32x4 acc = {0.0f, 0.0f, 0.0f, 0.0f};
                #pragma unroll
                for (int kc = 0; kc < 4; ++kc)
                    acc = __builtin_amdgcn_mfma_f32_16x16x32_bf16(Af[cti][kc], Bf[kc], acc, 0, 0, 0);
                #pragma unroll
                for (int r = 0; r < 4; ++r) {
                    float y = fminf(10.0f, fmaxf(-10.0f, acc[r]));
                    ob[cti][(size_t)r * L_TOT + s * 16] = y;
                }
            }
        }
        // ---------- wave 0: 16 recurrence steps of seg k ----------
        if (wid == 0 && k >= 0) {
            const float* xpk = xp[k & 1];
            unsigned* Hk = Hs[k & 1];
            float2 xr = *(const float2*)&xpk[m0];
            #pragma unroll
            for (int i = 0; i < 16; ++i) {
                float2 xn = xr;
                if (i < 15) xn = *(const float2*)&xpk[(i + 1) * 130 + m0];
                float p0 = fmaf(Vg1[0], hb, Vg0[0] * ha);
                float p1 = fmaf(Vg1[1], hb, Vg0[1] * ha);
                float p2 = fmaf(Vg1[2], hb, Vg0[2] * ha);
                float p3 = fmaf(Vg1[3], hb, Vg0[3] * ha);
                float p4 = fmaf(Vg1[4], hb, Vg0[4] * ha);
                float p5 = fmaf(Vg1[5], hb, Vg0[5] * ha);
                float p6 = fmaf(Vg1[6], hb, Vg0[6] * ha);
                float p7 = fmaf(Vg1[7], hb, Vg0[7] * ha);
                asm volatile(
                    "s_nop 1\n\t"
                    DPP_ROW("quad_perm:[1,0,3,2] row_mask:0xf bank_mask:0xf bound_ctrl:1")
                    DPP_ROW("quad_perm:[2,3,0,1] row_mask:0xf bank_mask:0xf bound_ctrl:1")
                    DPP_ROW("row_half_mirror row_mask:0xf bank_mask:0xf bound_ctrl:1")
                    DPP_ROW("row_mirror row_mask:0xf bank_mask:0xf bound_ctrl:1")
                    DPP_ROW("row_bcast:15 row_mask:0xa bank_mask:0xf")
                    DPP_ROW("row_bcast:31 row_mask:0xc bank_mask:0xf")
                    : "+v"(p0), "+v"(p1), "+v"(p2), "+v"(p3),
                      "+v"(p4), "+v"(p5), "+v"(p6), "+v"(p7));
                float v0 = __builtin_bit_cast(float, __builtin_amdgcn_readlane(__builtin_bit_cast(int, p0), 63));
                float v1 = __builtin_bit_cast(float, __builtin_amdgcn_readlane(__builtin_bit_cast(int, p1), 63));
                float v2 = __builtin_bit_cast(float, __builtin_amdgcn_readlane(__builtin_bit_cast(int, p2), 63));
                float v3 = __builtin_bit_cast(float, __builtin_amdgcn_readlane(__builtin_bit_cast(int, p3), 63));
                float v4 = __builtin_bit_cast(float, __builtin_amdgcn_readlane(__builtin_bit_cast(int, p4), 63));
                float v5 = __builtin_bit_cast(float, __builtin_amdgcn_readlane(__builtin_bit_cast(int, p5), 63));
                float v6 = __builtin_bit_cast(float, __builtin_amdgcn_readlane(__builtin_bit_cast(int, p6), 63));
                float v7 = __builtin_bit_cast(float, __builtin_amdgcn_readlane(__builtin_bit_cast(int, p7), 63));
                float q0 = fmaf(v1, Ug0[1], v0 * Ug0[0]);
                float q1 = fmaf(v3, Ug0[3], v2 * Ug0[2]);
                float q2 = fmaf(v5, Ug0[5], v4 * Ug0[4]);
                float q3 = fmaf(v7, Ug0[7], v6 * Ug0[6]);
                float av0 = (q0 + q1) + (q2 + q3);
                float s0 = fmaf(v1, Ug1[1], v0 * Ug1[0]);
                float s1 = fmaf(v3, Ug1[3], v2 * Ug1[2]);
                float s2 = fmaf(v5, Ug1[5], v4 * Ug1[4]);
                float s3 = fmaf(v7, Ug1[7], v6 * Ug1[6]);
                float av1 = (s0 + s1) + (s2 + s3);
                ha = fminf(10.0f, fmaxf(-10.0f, fmaf(a0, ha, av0) + xr.x));
                hb = fminf(10.0f, fmaxf(-10.0f, fmaf(a1, hb, av1) + xr.y));
                unsigned hp;
                asm("v_cvt_pk_bf16_f32 %0, %1, %2" : "=v"(hp) : "v"(ha), "v"(hb));
                Hk[i * 68 + lane] = hp;
                xr = xn;
            }
        }
        __syncthreads();
    }

    // ---------- tail: y for seg 31 ----------
    if (wid == 1 || wid == 2) {
        const int s = 31;
        const unsigned* Hp = Hs[s & 1];
        short8 Bf[4];
        #pragma unroll
        for (int kc = 0; kc < 4; ++kc)
            Bf[kc] = __builtin_bit_cast(short8,
                *(const uint4*)&Hp[row16 * 68 + kc * 16 + grp * 4]);
        #pragma unroll
        for (int cti = 0; cti < 2; ++cti) {
            f32x4 acc = {0.0f, 0.0f, 0.0f, 0.0f};
            #pragma unroll
            for (int kc = 0; kc < 4; ++kc)
                acc = __builtin_amdgcn_mfma_f32_16x16x32_bf16(Af[cti][kc], Bf[kc], acc, 0, 0, 0);
            #pragma unroll
            for (int r = 0; r < 4; ++r) {
                float y = fminf(10.0f, fmaxf(-10.0f, acc[r]));
                ob[cti][(size_t)r * L_TOT + s * 16] = y;
            }
        }
    }
}

extern "C" void kernel_launch(void* const* d_in, const int* in_sizes, int n_in,
                              void* d_out, int out_size, void* d_ws, size_t ws_size,
                              hipStream_t stream) {
    const float* x          = (const float*)d_in[0];
    const float* g          = (const float*)d_in[1];
    const float* in_proj_w  = (const float*)d_in[2];
    const float* in_proj_b  = (const float*)d_in[3];
    const float* out_proj_w = (const float*)d_in[4];
    const float* U_base     = (const float*)d_in[5];
    const float* V_base     = (const float*)d_in[6];
    const float* a_base     = (const float*)d_in[7];
    const float* mod_uv_w   = (const float*)d_in[8];
    const float* mod_uv_b   = (const float*)d_in[9];
    const float* mod_a_w    = (const float*)d_in[10];
    const float* mod_a_b    = (const float*)d_in[11];
    const float* mod_B_w    = (const float*)d_in[12];
    const float* mod_B_b    = (const float*)d_in[13];
    const float* mod_C_w    = (const float*)d_in[14];
    const float* mod_C_b    = (const float*)d_in[15];
    const float* h0         = (const float*)d_in[16];
    float* out = (float*)d_out;
    float* ws  = (float*)d_ws;

    hipLaunchKernelGGL(mod_kernel, dim3(4), dim3(128), 0, stream,
                       g, U_base, V_base, a_base, out_proj_w,
                       mod_uv_w, mod_uv_b, mod_a_w, mod_a_b,
                       mod_B_w, mod_B_b, mod_C_w, mod_C_b, ws);
    hipLaunchKernelGGL(fused_kernel, dim3(512), dim3(320), 0, stream,
                       x, in_proj_w, in_proj_b, ws,
                       (const unsigned*)(ws + WS_CGP), h0, out);
}

// Round 8
// 315.044 us; speedup vs baseline: 1.1387x; 1.1387x over previous
//
#include <hip/hip_runtime.h>

#define L_TOT 65536

// ws float offsets
#define WS_UG   0        // [4][128][8]
#define WS_VG   4096     // [4][128][8]
#define WS_A    8192     // [4][128]
#define WS_GB1  8704     // [4][128]
#define WS_CGP  32768    // uint[4][64][64]: packed bf16 pairs of Cg
#define WS_XS   65536    // [4][65536][128] fp32 x_seq

typedef __attribute__((ext_vector_type(8))) short short8;
typedef __attribute__((ext_vector_type(4))) float f32x4;

__device__ __forceinline__ unsigned bf16rne(float f) {
    unsigned u = __builtin_bit_cast(unsigned, f);
    return (u + 0x7fffu + ((u >> 16) & 1u)) >> 16;
}

#define DPP_ROW(CT) \
    "v_add_f32_dpp %0, %0, %0 " CT "\n\t" \
    "v_add_f32_dpp %1, %1, %1 " CT "\n\t" \
    "v_add_f32_dpp %2, %2, %2 " CT "\n\t" \
    "v_add_f32_dpp %3, %3, %3 " CT "\n\t" \
    "v_add_f32_dpp %4, %4, %4 " CT "\n\t" \
    "v_add_f32_dpp %5, %5, %5 " CT "\n\t" \
    "v_add_f32_dpp %6, %6, %6 " CT "\n\t" \
    "v_add_f32_dpp %7, %7, %7 " CT "\n\t"

__global__ __launch_bounds__(128) void mod_kernel(
    const float* __restrict__ g,
    const float* __restrict__ U_base, const float* __restrict__ V_base,
    const float* __restrict__ a_base, const float* __restrict__ out_proj_w,
    const float* __restrict__ mod_uv_w, const float* __restrict__ mod_uv_b,
    const float* __restrict__ mod_a_w, const float* __restrict__ mod_a_b,
    const float* __restrict__ mod_B_w, const float* __restrict__ mod_B_b,
    const float* __restrict__ mod_C_w, const float* __restrict__ mod_C_b,
    float* __restrict__ ws)
{
    __shared__ float gsh[64];
    __shared__ float uvs[16];
    __shared__ float gCs[64];
    const int b = blockIdx.x, tid = threadIdx.x;
    if (tid < 64) gsh[tid] = g[b * 64 + tid];
    __syncthreads();
    if (tid < 16) {
        float s = mod_uv_b[tid];
        for (int d = 0; d < 64; ++d) s += mod_uv_w[tid * 64 + d] * gsh[d];
        uvs[tid] = fminf(0.5f, fmaxf(-0.5f, s));
    }
    float ga_v, gB_v;
    {
        float s = mod_a_b[tid];
        for (int d = 0; d < 64; ++d) s += mod_a_w[tid * 64 + d] * gsh[d];
        ga_v = fminf(2.0f, fmaxf(-2.0f, s));
    }
    {
        float s = mod_B_b[tid];
        for (int d = 0; d < 64; ++d) s += mod_B_w[tid * 64 + d] * gsh[d];
        gB_v = 1.0f + fminf(1.0f, fmaxf(-1.0f, s));
    }
    if (tid < 64) {
        float s = mod_C_b[tid];
        for (int d = 0; d < 64; ++d) s += mod_C_w[tid * 64 + d] * gsh[d];
        gCs[tid] = 1.0f + fminf(0.5f, fmaxf(-0.5f, s));
    }
    __syncthreads();
    for (int idx = tid; idx < 1024; idx += 128) {
        int m = idx >> 3, r = idx & 7;
        ws[WS_UG + (b * 128 + m) * 8 + r] = U_base[m * 8 + r] * (1.0f + uvs[r]);
        ws[WS_VG + (b * 128 + m) * 8 + r] = V_base[m * 8 + r] * (1.0f + uvs[8 + r]);
    }
    ws[WS_A   + b * 128 + tid] = a_base[tid] + ga_v;
    ws[WS_GB1 + b * 128 + tid] = gB_v;
    unsigned* CgP = (unsigned*)(ws + WS_CGP);
    for (int idx = tid; idx < 4096; idx += 128) {
        int c = idx >> 6, j = idx & 63;
        float s = gCs[c];
        float c0 = out_proj_w[c * 128 + 2 * j]     * s;
        float c1 = out_proj_w[c * 128 + 2 * j + 1] * s;
        CgP[(b * 64 + c) * 64 + j] = bf16rne(c0) | (bf16rne(c1) << 16);
    }
}

__global__ __launch_bounds__(256) void inproj_kernel(
    const float* __restrict__ x, const float* __restrict__ W,
    const float* __restrict__ bias, const float* __restrict__ ws,
    float* __restrict__ xs)
{
    __shared__ float xsh[64][68];
    __shared__ float Wsh[128][65];
    const int tid = threadIdx.x;
    const int b = blockIdx.y;
    const int l0 = blockIdx.x * 64;

    for (int rep = 0; rep < 16; ++rep) {
        int idx = rep * 256 + tid;
        int c = idx >> 6, col = idx & 63;
        xsh[c][col] = x[((size_t)(b * 64 + c)) * L_TOT + l0 + col];
    }
    for (int rep = 0; rep < 32; ++rep) {
        int idx = rep * 256 + tid;
        Wsh[idx >> 6][idx & 63] = W[idx];
    }
    const int m = tid & 127, lg = tid >> 7;
    float acc[32];
    #pragma unroll
    for (int j = 0; j < 32; ++j) acc[j] = 0.0f;
    __syncthreads();

    for (int c = 0; c < 64; ++c) {
        float w = Wsh[m][c];
        #pragma unroll
        for (int j4 = 0; j4 < 8; ++j4) {
            float4 xv = *(const float4*)&xsh[c][lg * 32 + j4 * 4];
            acc[j4 * 4 + 0] += w * xv.x;
            acc[j4 * 4 + 1] += w * xv.y;
            acc[j4 * 4 + 2] += w * xv.z;
            acc[j4 * 4 + 3] += w * xv.w;
        }
    }
    const float gb1 = ws[WS_GB1 + b * 128 + m];
    const float bm = bias[m];
    #pragma unroll
    for (int j = 0; j < 32; ++j) {
        int l = l0 + lg * 32 + j;
        xs[((size_t)b * L_TOT + l) * 128 + m] = gb1 * (acc[j] + bm);
    }
}

// One recurrence step for one chunk (all-VALU; DPP reduce + readlane bcast).
__device__ __forceinline__ void step_one(
    float& ha, float& hb, const float2 xv,
    const float* __restrict__ Vg0, const float* __restrict__ Vg1,
    const float* __restrict__ Ug0, const float* __restrict__ Ug1,
    const float a0, const float a1, unsigned* __restrict__ Hrow)
{
    float p0 = fmaf(Vg1[0], hb, Vg0[0] * ha);
    float p1 = fmaf(Vg1[1], hb, Vg0[1] * ha);
    float p2 = fmaf(Vg1[2], hb, Vg0[2] * ha);
    float p3 = fmaf(Vg1[3], hb, Vg0[3] * ha);
    float p4 = fmaf(Vg1[4], hb, Vg0[4] * ha);
    float p5 = fmaf(Vg1[5], hb, Vg0[5] * ha);
    float p6 = fmaf(Vg1[6], hb, Vg0[6] * ha);
    float p7 = fmaf(Vg1[7], hb, Vg0[7] * ha);
    asm volatile(
        "s_nop 1\n\t"
        DPP_ROW("quad_perm:[1,0,3,2] row_mask:0xf bank_mask:0xf bound_ctrl:1")
        DPP_ROW("quad_perm:[2,3,0,1] row_mask:0xf bank_mask:0xf bound_ctrl:1")
        DPP_ROW("row_half_mirror row_mask:0xf bank_mask:0xf bound_ctrl:1")
        DPP_ROW("row_mirror row_mask:0xf bank_mask:0xf bound_ctrl:1")
        DPP_ROW("row_bcast:15 row_mask:0xa bank_mask:0xf")
        DPP_ROW("row_bcast:31 row_mask:0xc bank_mask:0xf")
        : "+v"(p0), "+v"(p1), "+v"(p2), "+v"(p3),
          "+v"(p4), "+v"(p5), "+v"(p6), "+v"(p7));
    float v0 = __builtin_bit_cast(float, __builtin_amdgcn_readlane(__builtin_bit_cast(int, p0), 63));
    float v1 = __builtin_bit_cast(float, __builtin_amdgcn_readlane(__builtin_bit_cast(int, p1), 63));
    float v2 = __builtin_bit_cast(float, __builtin_amdgcn_readlane(__builtin_bit_cast(int, p2), 63));
    float v3 = __builtin_bit_cast(float, __builtin_amdgcn_readlane(__builtin_bit_cast(int, p3), 63));
    float v4 = __builtin_bit_cast(float, __builtin_amdgcn_readlane(__builtin_bit_cast(int, p4), 63));
    float v5 = __builtin_bit_cast(float, __builtin_amdgcn_readlane(__builtin_bit_cast(int, p5), 63));
    float v6 = __builtin_bit_cast(float, __builtin_amdgcn_readlane(__builtin_bit_cast(int, p6), 63));
    float v7 = __builtin_bit_cast(float, __builtin_amdgcn_readlane(__builtin_bit_cast(int, p7), 63));
    float q0 = fmaf(v1, Ug0[1], v0 * Ug0[0]);
    float q1 = fmaf(v3, Ug0[3], v2 * Ug0[2]);
    float q2 = fmaf(v5, Ug0[5], v4 * Ug0[4]);
    float q3 = fmaf(v7, Ug0[7], v6 * Ug0[6]);
    float av0 = (q0 + q1) + (q2 + q3);
    float s0 = fmaf(v1, Ug1[1], v0 * Ug1[0]);
    float s1 = fmaf(v3, Ug1[3], v2 * Ug1[2]);
    float s2 = fmaf(v5, Ug1[5], v4 * Ug1[4]);
    float s3 = fmaf(v7, Ug1[7], v6 * Ug1[6]);
    float av1 = (s0 + s1) + (s2 + s3);
    ha = fminf(10.0f, fmaxf(-10.0f, fmaf(a0, ha, av0) + xv.x));
    hb = fminf(10.0f, fmaxf(-10.0f, fmaf(a1, hb, av1) + xv.y));
    unsigned hp;
    asm("v_cvt_pk_bf16_f32 %0, %1, %2" : "=v"(hp) : "v"(ha), "v"(hb));
    *Hrow = hp;
}

// TWO chunks (same b) per wave: 256 blocks x 64 threads. Steps of chunk A and
// chunk B interleave so B's issue hides A's DPP/readlane/memory latency.
// Params (Vg/Ug/a/Af) shared across the pair. MFMA y per chunk every 16 steps.
__global__ __launch_bounds__(64, 1) void scan_kernel(
    const float* __restrict__ xs, const float* __restrict__ ws,
    const unsigned* __restrict__ CgP, const float* __restrict__ h0,
    float* __restrict__ out)
{
    __shared__ __align__(16) unsigned Hs[2][16 * 68];
    const int lane = threadIdx.x;
    const int bb = blockIdx.x >> 6, kk = blockIdx.x & 63;
    const int m0 = 2 * lane;

    float Vg0[8], Vg1[8], Ug0[8], Ug1[8];
    {
        const float* vg = ws + WS_VG + (bb * 128 + m0) * 8;
        const float* ug = ws + WS_UG + (bb * 128 + m0) * 8;
        #pragma unroll
        for (int r = 0; r < 8; ++r) {
            Vg0[r] = vg[r]; Vg1[r] = vg[8 + r];
            Ug0[r] = ug[r]; Ug1[r] = ug[8 + r];
        }
    }
    const float a0 = ws[WS_A + bb * 128 + m0];
    const float a1 = ws[WS_A + bb * 128 + m0 + 1];
    float haA = h0[m0], hbA = h0[m0 + 1];
    float haB = haA,   hbB = hbA;

    short8 Af[4][4];
    const int row16 = lane & 15, grp = lane >> 4;
    {
        #pragma unroll
        for (int ct = 0; ct < 4; ++ct)
            #pragma unroll
            for (int kc = 0; kc < 4; ++kc) {
                const unsigned* p = CgP + (bb * 64 + ct * 16 + row16) * 64 + kc * 16 + grp * 4;
                Af[ct][kc] = __builtin_bit_cast(short8, *(const uint4*)p);
            }
    }

    const float* xspA = xs + ((size_t)bb * L_TOT + (size_t)kk * 1024) * 128;
    const float* xspB = xspA + 512 * 128;
    float* ob[4];
    #pragma unroll
    for (int ct = 0; ct < 4; ++ct)
        ob[ct] = out + (size_t)(bb * 64 + ct * 16 + grp * 4) * L_TOT + kk * 1024 + row16;

    float2 xqA[16], xqB[16];
    #pragma unroll
    for (int i = 0; i < 16; ++i) {
        xqA[i] = *(const float2*)(xspA + (size_t)i * 128 + m0);
        xqB[i] = *(const float2*)(xspB + (size_t)i * 128 + m0);
    }

    #pragma unroll 1
    for (int t16 = 0; t16 < 32; ++t16) {
        #pragma unroll
        for (int i = 0; i < 16; ++i) {
            step_one(haA, hbA, xqA[i], Vg0, Vg1, Ug0, Ug1, a0, a1, &Hs[0][i * 68 + lane]);
            step_one(haB, hbB, xqB[i], Vg0, Vg1, Ug0, Ug1, a0, a1, &Hs[1][i * 68 + lane]);
        }
        // B fragments
        short8 BfA[4], BfB[4];
        #pragma unroll
        for (int kc = 0; kc < 4; ++kc) {
            BfA[kc] = __builtin_bit_cast(short8, *(const uint4*)&Hs[0][row16 * 68 + kc * 16 + grp * 4]);
            BfB[kc] = __builtin_bit_cast(short8, *(const uint4*)&Hs[1][row16 * 68 + kc * 16 + grp * 4]);
        }
        // prefetch next segment's x (issued BEFORE the y stores)
        {
            const int tn = (t16 + 1) & 31;
            const float* xa = xspA + (size_t)tn * 16 * 128;
            const float* xb = xspB + (size_t)tn * 16 * 128;
            #pragma unroll
            for (int i = 0; i < 16; ++i) {
                xqA[i] = *(const float2*)(xa + (size_t)i * 128 + m0);
                xqB[i] = *(const float2*)(xb + (size_t)i * 128 + m0);
            }
        }
        // y = clip(Cg * H16) via MFMA, store both chunks
        #pragma unroll
        for (int ct = 0; ct < 4; ++ct) {
            f32x4 accA = {0.0f, 0.0f, 0.0f, 0.0f};
            f32x4 accB = {0.0f, 0.0f, 0.0f, 0.0f};
            #pragma unroll
            for (int kc = 0; kc < 4; ++kc) {
                accA = __builtin_amdgcn_mfma_f32_16x16x32_bf16(Af[ct][kc], BfA[kc], accA, 0, 0, 0);
                accB = __builtin_amdgcn_mfma_f32_16x16x32_bf16(Af[ct][kc], BfB[kc], accB, 0, 0, 0);
            }
            #pragma unroll
            for (int r = 0; r < 4; ++r) {
                float yA = fminf(10.0f, fmaxf(-10.0f, accA[r]));
                float yB = fminf(10.0f, fmaxf(-10.0f, accB[r]));
                ob[ct][(size_t)r * L_TOT + t16 * 16] = yA;
                ob[ct][(size_t)r * L_TOT + t16 * 16 + 512] = yB;
            }
        }
    }
}

extern "C" void kernel_launch(void* const* d_in, const int* in_sizes, int n_in,
                              void* d_out, int out_size, void* d_ws, size_t ws_size,
                              hipStream_t stream) {
    const float* x          = (const float*)d_in[0];
    const float* g          = (const float*)d_in[1];
    const float* in_proj_w  = (const float*)d_in[2];
    const float* in_proj_b  = (const float*)d_in[3];
    const float* out_proj_w = (const float*)d_in[4];
    const float* U_base     = (const float*)d_in[5];
    const float* V_base     = (const float*)d_in[6];
    const float* a_base     = (const float*)d_in[7];
    const float* mod_uv_w   = (const float*)d_in[8];
    const float* mod_uv_b   = (const float*)d_in[9];
    const float* mod_a_w    = (const float*)d_in[10];
    const float* mod_a_b    = (const float*)d_in[11];
    const float* mod_B_w    = (const float*)d_in[12];
    const float* mod_B_b    = (const float*)d_in[13];
    const float* mod_C_w    = (const float*)d_in[14];
    const float* mod_C_b    = (const float*)d_in[15];
    const float* h0         = (const float*)d_in[16];
    float* out = (float*)d_out;
    float* ws  = (float*)d_ws;

    hipLaunchKernelGGL(mod_kernel, dim3(4), dim3(128), 0, stream,
                       g, U_base, V_base, a_base, out_proj_w,
                       mod_uv_w, mod_uv_b, mod_a_w, mod_a_b,
                       mod_B_w, mod_B_b, mod_C_w, mod_C_b, ws);
    hipLaunchKernelGGL(inproj_kernel, dim3(1024, 4), dim3(256), 0, stream,
                       x, in_proj_w, in_proj_b, ws, ws + WS_XS);
    hipLaunchKernelGGL(scan_kernel, dim3(256), dim3(64), 0, stream,
                       ws + WS_XS, ws, (const unsigned*)(ws + WS_CGP), h0, out);
}

// Round 9
// 195.837 us; speedup vs baseline: 1.8318x; 1.6087x over previous
//
#include <hip/hip_runtime.h>
#include <hip/hip_fp16.h>

#define L_TOT 65536

// ws float offsets
#define WS_UG   0        // [4][128][8]
#define WS_VG   4096     // [4][128][8]
#define WS_A    8192     // [4][128]
#define WS_GB1  8704     // [4][128]
#define WS_CGP  32768    // uint[4][64][64]: packed bf16 pairs of Cg
#define WS_XS   65536    // uint[4][65536][64]: packed fp16 m-pairs of x_seq (67MB)

typedef __attribute__((ext_vector_type(8))) short short8;
typedef __attribute__((ext_vector_type(4))) float f32x4;

__device__ __forceinline__ unsigned bf16rne(float f) {
    unsigned u = __builtin_bit_cast(unsigned, f);
    return (u + 0x7fffu + ((u >> 16) & 1u)) >> 16;
}

#define DPP_ROW(CT) \
    "v_add_f32_dpp %0, %0, %0 " CT "\n\t" \
    "v_add_f32_dpp %1, %1, %1 " CT "\n\t" \
    "v_add_f32_dpp %2, %2, %2 " CT "\n\t" \
    "v_add_f32_dpp %3, %3, %3 " CT "\n\t" \
    "v_add_f32_dpp %4, %4, %4 " CT "\n\t" \
    "v_add_f32_dpp %5, %5, %5 " CT "\n\t" \
    "v_add_f32_dpp %6, %6, %6 " CT "\n\t" \
    "v_add_f32_dpp %7, %7, %7 " CT "\n\t"

__global__ __launch_bounds__(128) void mod_kernel(
    const float* __restrict__ g,
    const float* __restrict__ U_base, const float* __restrict__ V_base,
    const float* __restrict__ a_base, const float* __restrict__ out_proj_w,
    const float* __restrict__ mod_uv_w, const float* __restrict__ mod_uv_b,
    const float* __restrict__ mod_a_w, const float* __restrict__ mod_a_b,
    const float* __restrict__ mod_B_w, const float* __restrict__ mod_B_b,
    const float* __restrict__ mod_C_w, const float* __restrict__ mod_C_b,
    float* __restrict__ ws)
{
    __shared__ float gsh[64];
    __shared__ float uvs[16];
    __shared__ float gCs[64];
    const int b = blockIdx.x, tid = threadIdx.x;
    if (tid < 64) gsh[tid] = g[b * 64 + tid];
    __syncthreads();
    if (tid < 16) {
        float s = mod_uv_b[tid];
        for (int d = 0; d < 64; ++d) s += mod_uv_w[tid * 64 + d] * gsh[d];
        uvs[tid] = fminf(0.5f, fmaxf(-0.5f, s));
    }
    float ga_v, gB_v;
    {
        float s = mod_a_b[tid];
        for (int d = 0; d < 64; ++d) s += mod_a_w[tid * 64 + d] * gsh[d];
        ga_v = fminf(2.0f, fmaxf(-2.0f, s));
    }
    {
        float s = mod_B_b[tid];
        for (int d = 0; d < 64; ++d) s += mod_B_w[tid * 64 + d] * gsh[d];
        gB_v = 1.0f + fminf(1.0f, fmaxf(-1.0f, s));
    }
    if (tid < 64) {
        float s = mod_C_b[tid];
        for (int d = 0; d < 64; ++d) s += mod_C_w[tid * 64 + d] * gsh[d];
        gCs[tid] = 1.0f + fminf(0.5f, fmaxf(-0.5f, s));
    }
    __syncthreads();
    for (int idx = tid; idx < 1024; idx += 128) {
        int m = idx >> 3, r = idx & 7;
        ws[WS_UG + (b * 128 + m) * 8 + r] = U_base[m * 8 + r] * (1.0f + uvs[r]);
        ws[WS_VG + (b * 128 + m) * 8 + r] = V_base[m * 8 + r] * (1.0f + uvs[8 + r]);
    }
    ws[WS_A   + b * 128 + tid] = a_base[tid] + ga_v;
    ws[WS_GB1 + b * 128 + tid] = gB_v;
    unsigned* CgP = (unsigned*)(ws + WS_CGP);
    for (int idx = tid; idx < 4096; idx += 128) {
        int c = idx >> 6, j = idx & 63;
        float s = gCs[c];
        float c0 = out_proj_w[c * 128 + 2 * j]     * s;
        float c1 = out_proj_w[c * 128 + 2 * j + 1] * s;
        CgP[(b * 64 + c) * 64 + j] = bf16rne(c0) | (bf16rne(c1) << 16);
    }
}

// x_seq packed fp16: xs16[(b*L + l)*64 + mp] = pk(f16(v_{2mp}), f16(v_{2mp+1}))
// thread: m-pair mp = tid&63, l-quarter lq = tid>>6 (16 l's each).
__global__ __launch_bounds__(256) void inproj_kernel(
    const float* __restrict__ x, const float* __restrict__ W,
    const float* __restrict__ bias, const float* __restrict__ ws,
    unsigned* __restrict__ xs16)
{
    __shared__ float xsh[64][68];
    __shared__ float Wsh[128][65];
    const int tid = threadIdx.x;
    const int b = blockIdx.y;
    const int l0 = blockIdx.x * 64;

    for (int rep = 0; rep < 16; ++rep) {
        int idx = rep * 256 + tid;
        int c = idx >> 6, col = idx & 63;
        xsh[c][col] = x[((size_t)(b * 64 + c)) * L_TOT + l0 + col];
    }
    for (int rep = 0; rep < 32; ++rep) {
        int idx = rep * 256 + tid;
        Wsh[idx >> 6][idx & 63] = W[idx];
    }
    const int mp = tid & 63, lq = tid >> 6;
    const int m0 = 2 * mp;
    float acc0[16], acc1[16];
    #pragma unroll
    for (int j = 0; j < 16; ++j) { acc0[j] = 0.0f; acc1[j] = 0.0f; }
    __syncthreads();

    for (int c = 0; c < 64; ++c) {
        float w0 = Wsh[m0][c], w1 = Wsh[m0 + 1][c];
        #pragma unroll
        for (int j4 = 0; j4 < 4; ++j4) {
            float4 xv = *(const float4*)&xsh[c][lq * 16 + j4 * 4];
            acc0[j4 * 4 + 0] = fmaf(w0, xv.x, acc0[j4 * 4 + 0]);
            acc0[j4 * 4 + 1] = fmaf(w0, xv.y, acc0[j4 * 4 + 1]);
            acc0[j4 * 4 + 2] = fmaf(w0, xv.z, acc0[j4 * 4 + 2]);
            acc0[j4 * 4 + 3] = fmaf(w0, xv.w, acc0[j4 * 4 + 3]);
            acc1[j4 * 4 + 0] = fmaf(w1, xv.x, acc1[j4 * 4 + 0]);
            acc1[j4 * 4 + 1] = fmaf(w1, xv.y, acc1[j4 * 4 + 1]);
            acc1[j4 * 4 + 2] = fmaf(w1, xv.z, acc1[j4 * 4 + 2]);
            acc1[j4 * 4 + 3] = fmaf(w1, xv.w, acc1[j4 * 4 + 3]);
        }
    }
    const float gb0 = ws[WS_GB1 + b * 128 + m0];
    const float gb1 = ws[WS_GB1 + b * 128 + m0 + 1];
    const float b0 = bias[m0], b1 = bias[m0 + 1];
    #pragma unroll
    for (int j = 0; j < 16; ++j) {
        int l = l0 + lq * 16 + j;
        float v0 = (acc0[j] + b0) * gb0;
        float v1 = (acc1[j] + b1) * gb1;
        __half2 hp = __floats2half2_rn(v0, v1);
        xs16[((size_t)b * L_TOT + l) * 64 + mp] = __builtin_bit_cast(unsigned, hp);
    }
}

// One WAVE per (b, chunk), round-6 structure. x from packed fp16 (1 dword/step).
__global__ __launch_bounds__(64, 1) void scan_kernel(
    const unsigned* __restrict__ xs16, const float* __restrict__ ws,
    const unsigned* __restrict__ CgP, const float* __restrict__ h0,
    float* __restrict__ out)
{
    __shared__ __align__(16) unsigned Hs[16 * 68];
    const int lane = threadIdx.x;
    const int bb = blockIdx.x >> 7, k = blockIdx.x & 127;
    const int m0 = 2 * lane;

    float Vg0[8], Vg1[8], Ug0[8], Ug1[8];
    {
        const float* vg = ws + WS_VG + (bb * 128 + m0) * 8;
        const float* ug = ws + WS_UG + (bb * 128 + m0) * 8;
        #pragma unroll
        for (int r = 0; r < 8; ++r) {
            Vg0[r] = vg[r]; Vg1[r] = vg[8 + r];
            Ug0[r] = ug[r]; Ug1[r] = ug[8 + r];
        }
    }
    const float a0 = ws[WS_A + bb * 128 + m0];
    const float a1 = ws[WS_A + bb * 128 + m0 + 1];
    float ha = h0[m0], hb = h0[m0 + 1];

    short8 Af[4][4];
    const int row16 = lane & 15, grp = lane >> 4;
    {
        #pragma unroll
        for (int ct = 0; ct < 4; ++ct)
            #pragma unroll
            for (int kc = 0; kc < 4; ++kc) {
                const unsigned* p = CgP + (bb * 64 + ct * 16 + row16) * 64 + kc * 16 + grp * 4;
                Af[ct][kc] = __builtin_bit_cast(short8, *(const uint4*)p);
            }
    }

    const unsigned* xsp = xs16 + ((size_t)bb * L_TOT + (size_t)k * 512) * 64 + lane;
    float* ob[4];
    #pragma unroll
    for (int ct = 0; ct < 4; ++ct)
        ob[ct] = out + (size_t)(bb * 64 + ct * 16 + grp * 4) * L_TOT + k * 512 + row16;

    unsigned xq[16];
    #pragma unroll
    for (int i = 0; i < 16; ++i)
        xq[i] = xsp[(size_t)i * 64];

    #pragma unroll 1
    for (int t16 = 0; t16 < 32; ++t16) {
        #pragma unroll
        for (int i = 0; i < 16; ++i) {
            const float2 xv = __half22float2(__builtin_bit_cast(__half2, xq[i]));
            float p0 = fmaf(Vg1[0], hb, Vg0[0] * ha);
            float p1 = fmaf(Vg1[1], hb, Vg0[1] * ha);
            float p2 = fmaf(Vg1[2], hb, Vg0[2] * ha);
            float p3 = fmaf(Vg1[3], hb, Vg0[3] * ha);
            float p4 = fmaf(Vg1[4], hb, Vg0[4] * ha);
            float p5 = fmaf(Vg1[5], hb, Vg0[5] * ha);
            float p6 = fmaf(Vg1[6], hb, Vg0[6] * ha);
            float p7 = fmaf(Vg1[7], hb, Vg0[7] * ha);
            asm volatile(
                "s_nop 1\n\t"
                DPP_ROW("quad_perm:[1,0,3,2] row_mask:0xf bank_mask:0xf bound_ctrl:1")
                DPP_ROW("quad_perm:[2,3,0,1] row_mask:0xf bank_mask:0xf bound_ctrl:1")
                DPP_ROW("row_half_mirror row_mask:0xf bank_mask:0xf bound_ctrl:1")
                DPP_ROW("row_mirror row_mask:0xf bank_mask:0xf bound_ctrl:1")
                DPP_ROW("row_bcast:15 row_mask:0xa bank_mask:0xf")
                DPP_ROW("row_bcast:31 row_mask:0xc bank_mask:0xf")
                : "+v"(p0), "+v"(p1), "+v"(p2), "+v"(p3),
                  "+v"(p4), "+v"(p5), "+v"(p6), "+v"(p7));
            float v0 = __builtin_bit_cast(float, __builtin_amdgcn_readlane(__builtin_bit_cast(int, p0), 63));
            float v1 = __builtin_bit_cast(float, __builtin_amdgcn_readlane(__builtin_bit_cast(int, p1), 63));
            float v2 = __builtin_bit_cast(float, __builtin_amdgcn_readlane(__builtin_bit_cast(int, p2), 63));
            float v3 = __builtin_bit_cast(float, __builtin_amdgcn_readlane(__builtin_bit_cast(int, p3), 63));
            float v4 = __builtin_bit_cast(float, __builtin_amdgcn_readlane(__builtin_bit_cast(int, p4), 63));
            float v5 = __builtin_bit_cast(float, __builtin_amdgcn_readlane(__builtin_bit_cast(int, p5), 63));
            float v6 = __builtin_bit_cast(float, __builtin_amdgcn_readlane(__builtin_bit_cast(int, p6), 63));
            float v7 = __builtin_bit_cast(float, __builtin_amdgcn_readlane(__builtin_bit_cast(int, p7), 63));
            float q0 = fmaf(v1, Ug0[1], v0 * Ug0[0]);
            float q1 = fmaf(v3, Ug0[3], v2 * Ug0[2]);
            float q2 = fmaf(v5, Ug0[5], v4 * Ug0[4]);
            float q3 = fmaf(v7, Ug0[7], v6 * Ug0[6]);
            float av0 = (q0 + q1) + (q2 + q3);
            float s0 = fmaf(v1, Ug1[1], v0 * Ug1[0]);
            float s1 = fmaf(v3, Ug1[3], v2 * Ug1[2]);
            float s2 = fmaf(v5, Ug1[5], v4 * Ug1[4]);
            float s3 = fmaf(v7, Ug1[7], v6 * Ug1[6]);
            float av1 = (s0 + s1) + (s2 + s3);
            ha = fminf(10.0f, fmaxf(-10.0f, fmaf(a0, ha, av0) + xv.x));
            hb = fminf(10.0f, fmaxf(-10.0f, fmaf(a1, hb, av1) + xv.y));
            unsigned hp;
            asm("v_cvt_pk_bf16_f32 %0, %1, %2" : "=v"(hp) : "v"(ha), "v"(hb));
            Hs[i * 68 + lane] = hp;
        }
        // B fragments from Hs
        short8 Bf[4];
        #pragma unroll
        for (int kc = 0; kc < 4; ++kc)
            Bf[kc] = __builtin_bit_cast(short8,
                *(const uint4*)&Hs[row16 * 68 + kc * 16 + grp * 4]);
        // prefetch next 16 x dwords (issued BEFORE the y stores)
        {
            const int tn = (t16 + 1) & 31;
            const unsigned* xb = xsp + (size_t)tn * 16 * 64;
            #pragma unroll
            for (int i = 0; i < 16; ++i)
                xq[i] = xb[(size_t)i * 64];
        }
        // y = clip(Cg * H16) via MFMA, store
        #pragma unroll
        for (int ct = 0; ct < 4; ++ct) {
            f32x4 acc = {0.0f, 0.0f, 0.0f, 0.0f};
            #pragma unroll
            for (int kc = 0; kc < 4; ++kc)
                acc = __builtin_amdgcn_mfma_f32_16x16x32_bf16(Af[ct][kc], Bf[kc], acc, 0, 0, 0);
            #pragma unroll
            for (int r = 0; r < 4; ++r) {
                float y = fminf(10.0f, fmaxf(-10.0f, acc[r]));
                ob[ct][(size_t)r * L_TOT + t16 * 16] = y;
            }
        }
    }
}

extern "C" void kernel_launch(void* const* d_in, const int* in_sizes, int n_in,
                              void* d_out, int out_size, void* d_ws, size_t ws_size,
                              hipStream_t stream) {
    const float* x          = (const float*)d_in[0];
    const float* g          = (const float*)d_in[1];
    const float* in_proj_w  = (const float*)d_in[2];
    const float* in_proj_b  = (const float*)d_in[3];
    const float* out_proj_w = (const float*)d_in[4];
    const float* U_base     = (const float*)d_in[5];
    const float* V_base     = (const float*)d_in[6];
    const float* a_base     = (const float*)d_in[7];
    const float* mod_uv_w   = (const float*)d_in[8];
    const float* mod_uv_b   = (const float*)d_in[9];
    const float* mod_a_w    = (const float*)d_in[10];
    const float* mod_a_b    = (const float*)d_in[11];
    const float* mod_B_w    = (const float*)d_in[12];
    const float* mod_B_b    = (const float*)d_in[13];
    const float* mod_C_w    = (const float*)d_in[14];
    const float* mod_C_b    = (const float*)d_in[15];
    const float* h0         = (const float*)d_in[16];
    float* out = (float*)d_out;
    float* ws  = (float*)d_ws;
    unsigned* xs16 = (unsigned*)(ws + WS_XS);

    hipLaunchKernelGGL(mod_kernel, dim3(4), dim3(128), 0, stream,
                       g, U_base, V_base, a_base, out_proj_w,
                       mod_uv_w, mod_uv_b, mod_a_w, mod_a_b,
                       mod_B_w, mod_B_b, mod_C_w, mod_C_b, ws);
    hipLaunchKernelGGL(inproj_kernel, dim3(1024, 4), dim3(256), 0, stream,
                       x, in_proj_w, in_proj_b, ws, xs16);
    hipLaunchKernelGGL(scan_kernel, dim3(512), dim3(64), 0, stream,
                       xs16, ws, (const unsigned*)(ws + WS_CGP), h0, out);
}

// Round 11
// 191.742 us; speedup vs baseline: 1.8709x; 1.0214x over previous
//
#include <hip/hip_runtime.h>
#include <hip/hip_fp16.h>

#define L_TOT 65536

// ws float offsets
#define WS_UG   0        // [4][128][8]
#define WS_VG   4096     // [4][128][8]
#define WS_A    8192     // [4][128]
#define WS_GB1  8704     // [4][128]
#define WS_CGP  32768    // uint[4][64][64]: packed bf16 pairs of Cg
#define WS_XS   65536    // uint[4][65536][64]: packed fp16 m-pairs of x_seq

typedef __attribute__((ext_vector_type(8))) short short8;
typedef __attribute__((ext_vector_type(4))) float f32x4;

__device__ __forceinline__ unsigned bf16rne(float f) {
    unsigned u = __builtin_bit_cast(unsigned, f);
    return (u + 0x7fffu + ((u >> 16) & 1u)) >> 16;
}

#define DPP_ROW(CT) \
    "v_add_f32_dpp %0, %0, %0 " CT "\n\t" \
    "v_add_f32_dpp %1, %1, %1 " CT "\n\t" \
    "v_add_f32_dpp %2, %2, %2 " CT "\n\t" \
    "v_add_f32_dpp %3, %3, %3 " CT "\n\t" \
    "v_add_f32_dpp %4, %4, %4 " CT "\n\t" \
    "v_add_f32_dpp %5, %5, %5 " CT "\n\t" \
    "v_add_f32_dpp %6, %6, %6 " CT "\n\t" \
    "v_add_f32_dpp %7, %7, %7 " CT "\n\t"

__global__ __launch_bounds__(128) void mod_kernel(
    const float* __restrict__ g,
    const float* __restrict__ U_base, const float* __restrict__ V_base,
    const float* __restrict__ a_base, const float* __restrict__ out_proj_w,
    const float* __restrict__ mod_uv_w, const float* __restrict__ mod_uv_b,
    const float* __restrict__ mod_a_w, const float* __restrict__ mod_a_b,
    const float* __restrict__ mod_B_w, const float* __restrict__ mod_B_b,
    const float* __restrict__ mod_C_w, const float* __restrict__ mod_C_b,
    float* __restrict__ ws)
{
    __shared__ float gsh[64];
    __shared__ float uvs[16];
    __shared__ float gCs[64];
    const int b = blockIdx.x, tid = threadIdx.x;
    if (tid < 64) gsh[tid] = g[b * 64 + tid];
    __syncthreads();
    if (tid < 16) {
        float s = mod_uv_b[tid];
        for (int d = 0; d < 64; ++d) s += mod_uv_w[tid * 64 + d] * gsh[d];
        uvs[tid] = fminf(0.5f, fmaxf(-0.5f, s));
    }
    float ga_v, gB_v;
    {
        float s = mod_a_b[tid];
        for (int d = 0; d < 64; ++d) s += mod_a_w[tid * 64 + d] * gsh[d];
        ga_v = fminf(2.0f, fmaxf(-2.0f, s));
    }
    {
        float s = mod_B_b[tid];
        for (int d = 0; d < 64; ++d) s += mod_B_w[tid * 64 + d] * gsh[d];
        gB_v = 1.0f + fminf(1.0f, fmaxf(-1.0f, s));
    }
    if (tid < 64) {
        float s = mod_C_b[tid];
        for (int d = 0; d < 64; ++d) s += mod_C_w[tid * 64 + d] * gsh[d];
        gCs[tid] = 1.0f + fminf(0.5f, fmaxf(-0.5f, s));
    }
    __syncthreads();
    for (int idx = tid; idx < 1024; idx += 128) {
        int m = idx >> 3, r = idx & 7;
        ws[WS_UG + (b * 128 + m) * 8 + r] = U_base[m * 8 + r] * (1.0f + uvs[r]);
        ws[WS_VG + (b * 128 + m) * 8 + r] = V_base[m * 8 + r] * (1.0f + uvs[8 + r]);
    }
    ws[WS_A   + b * 128 + tid] = a_base[tid] + ga_v;
    ws[WS_GB1 + b * 128 + tid] = gB_v;
    unsigned* CgP = (unsigned*)(ws + WS_CGP);
    for (int idx = tid; idx < 4096; idx += 128) {
        int c = idx >> 6, j = idx & 63;
        float s = gCs[c];
        float c0 = out_proj_w[c * 128 + 2 * j]     * s;
        float c1 = out_proj_w[c * 128 + 2 * j + 1] * s;
        CgP[(b * 64 + c) * 64 + j] = bf16rne(c0) | (bf16rne(c1) << 16);
    }
}

// x_seq packed fp16: xs16[(b*L + l)*64 + mp] = pk(f16(v_{2mp}), f16(v_{2mp+1}))
// Compute loop bit-identical to round 9 (passing); staging vectorized only.
__global__ __launch_bounds__(256) void inproj_kernel(
    const float* __restrict__ x, const float* __restrict__ W,
    const float* __restrict__ bias, const float* __restrict__ ws,
    unsigned* __restrict__ xs16)
{
    __shared__ float xsh[64][68];
    __shared__ float Wsh[128][65];
    const int tid = threadIdx.x;
    const int b = blockIdx.y;
    const int l0 = blockIdx.x * 64;

    // x staging: float4 loads, same LDS contents as round 9
    #pragma unroll
    for (int rep = 0; rep < 4; ++rep) {
        int idx = rep * 256 + tid;             // 0..1023
        int c = idx >> 4, p = idx & 15;
        float4 v = *(const float4*)(x + (size_t)(b * 64 + c) * L_TOT + l0 + p * 4);
        *(float4*)&xsh[c][p * 4] = v;          // c*68 + 4p -> 16B aligned
    }
    // W staging: float4 global loads, scalar LDS writes (padded [65] layout kept)
    #pragma unroll
    for (int rep = 0; rep < 8; ++rep) {
        int idx = rep * 256 + tid;             // 0..2047
        int m = idx >> 4, c4 = (idx & 15) * 4;
        float4 wv = *(const float4*)(W + m * 64 + c4);
        Wsh[m][c4]     = wv.x;
        Wsh[m][c4 + 1] = wv.y;
        Wsh[m][c4 + 2] = wv.z;
        Wsh[m][c4 + 3] = wv.w;
    }
    const int mp = tid & 63, lq = tid >> 6;
    const int m0 = 2 * mp;
    float acc0[16], acc1[16];
    #pragma unroll
    for (int j = 0; j < 16; ++j) { acc0[j] = 0.0f; acc1[j] = 0.0f; }
    __syncthreads();

    for (int c = 0; c < 64; ++c) {
        float w0 = Wsh[m0][c], w1 = Wsh[m0 + 1][c];
        #pragma unroll
        for (int j4 = 0; j4 < 4; ++j4) {
            float4 xv = *(const float4*)&xsh[c][lq * 16 + j4 * 4];
            acc0[j4 * 4 + 0] = fmaf(w0, xv.x, acc0[j4 * 4 + 0]);
            acc0[j4 * 4 + 1] = fmaf(w0, xv.y, acc0[j4 * 4 + 1]);
            acc0[j4 * 4 + 2] = fmaf(w0, xv.z, acc0[j4 * 4 + 2]);
            acc0[j4 * 4 + 3] = fmaf(w0, xv.w, acc0[j4 * 4 + 3]);
            acc1[j4 * 4 + 0] = fmaf(w1, xv.x, acc1[j4 * 4 + 0]);
            acc1[j4 * 4 + 1] = fmaf(w1, xv.y, acc1[j4 * 4 + 1]);
            acc1[j4 * 4 + 2] = fmaf(w1, xv.z, acc1[j4 * 4 + 2]);
            acc1[j4 * 4 + 3] = fmaf(w1, xv.w, acc1[j4 * 4 + 3]);
        }
    }
    const float gb0 = ws[WS_GB1 + b * 128 + m0];
    const float gb1 = ws[WS_GB1 + b * 128 + m0 + 1];
    const float b0 = bias[m0], b1 = bias[m0 + 1];
    #pragma unroll
    for (int j = 0; j < 16; ++j) {
        int l = l0 + lq * 16 + j;
        float v0 = (acc0[j] + b0) * gb0;
        float v1 = (acc1[j] + b1) * gb1;
        __half2 hp = __floats2half2_rn(v0, v1);
        xs16[((size_t)b * L_TOT + l) * 64 + mp] = __builtin_bit_cast(unsigned, hp);
    }
}

// One WAVE per (b, chunk). Fused-DPP all-reduce recurrence; xq double-buffered
// (next segment's loads issued BEFORE current segment's 16 steps). MFMA y
// every 16 steps.
__global__ __launch_bounds__(64, 1) void scan_kernel(
    const unsigned* __restrict__ xs16, const float* __restrict__ ws,
    const unsigned* __restrict__ CgP, const float* __restrict__ h0,
    float* __restrict__ out)
{
    __shared__ __align__(16) unsigned Hs[16 * 68];
    const int lane = threadIdx.x;
    const int bb = blockIdx.x >> 7, k = blockIdx.x & 127;
    const int m0 = 2 * lane;

    float Vg0[8], Vg1[8], Ug0[8], Ug1[8];
    {
        const float* vg = ws + WS_VG + (bb * 128 + m0) * 8;
        const float* ug = ws + WS_UG + (bb * 128 + m0) * 8;
        #pragma unroll
        for (int r = 0; r < 8; ++r) {
            Vg0[r] = vg[r]; Vg1[r] = vg[8 + r];
            Ug0[r] = ug[r]; Ug1[r] = ug[8 + r];
        }
    }
    const float a0 = ws[WS_A + bb * 128 + m0];
    const float a1 = ws[WS_A + bb * 128 + m0 + 1];
    float ha = h0[m0], hb = h0[m0 + 1];

    short8 Af[4][4];
    const int row16 = lane & 15, grp = lane >> 4;
    #pragma unroll
    for (int ct = 0; ct < 4; ++ct)
        #pragma unroll
        for (int kc = 0; kc < 4; ++kc) {
            const unsigned* p = CgP + (bb * 64 + ct * 16 + row16) * 64 + kc * 16 + grp * 4;
            Af[ct][kc] = __builtin_bit_cast(short8, *(const uint4*)p);
        }

    const unsigned* xsp = xs16 + ((size_t)bb * L_TOT + (size_t)k * 512) * 64 + lane;
    float* ob[4];
    #pragma unroll
    for (int ct = 0; ct < 4; ++ct)
        ob[ct] = out + (size_t)(bb * 64 + ct * 16 + grp * 4) * L_TOT + k * 512 + row16;

    unsigned xqA[16], xqB[16];

    auto prefetch = [&](unsigned (&xq)[16], int seg) {
        const unsigned* xb = xsp + (size_t)seg * 1024;   // 16*64
        #pragma unroll
        for (int i = 0; i < 16; ++i) xq[i] = xb[(size_t)i * 64];
    };
    auto do_seg = [&](const unsigned (&xq)[16], int t16) {
        #pragma unroll
        for (int i = 0; i < 16; ++i) {
            const float2 xv = __half22float2(__builtin_bit_cast(__half2, xq[i]));
            float p0 = fmaf(Vg1[0], hb, Vg0[0] * ha);
            float p1 = fmaf(Vg1[1], hb, Vg0[1] * ha);
            float p2 = fmaf(Vg1[2], hb, Vg0[2] * ha);
            float p3 = fmaf(Vg1[3], hb, Vg0[3] * ha);
            float p4 = fmaf(Vg1[4], hb, Vg0[4] * ha);
            float p5 = fmaf(Vg1[5], hb, Vg0[5] * ha);
            float p6 = fmaf(Vg1[6], hb, Vg0[6] * ha);
            float p7 = fmaf(Vg1[7], hb, Vg0[7] * ha);
            asm volatile(
                "s_nop 1\n\t"
                DPP_ROW("quad_perm:[1,0,3,2] row_mask:0xf bank_mask:0xf bound_ctrl:1")
                DPP_ROW("quad_perm:[2,3,0,1] row_mask:0xf bank_mask:0xf bound_ctrl:1")
                DPP_ROW("row_half_mirror row_mask:0xf bank_mask:0xf bound_ctrl:1")
                DPP_ROW("row_mirror row_mask:0xf bank_mask:0xf bound_ctrl:1")
                DPP_ROW("row_bcast:15 row_mask:0xa bank_mask:0xf")
                DPP_ROW("row_bcast:31 row_mask:0xc bank_mask:0xf")
                : "+v"(p0), "+v"(p1), "+v"(p2), "+v"(p3),
                  "+v"(p4), "+v"(p5), "+v"(p6), "+v"(p7));
            float v0 = __builtin_bit_cast(float, __builtin_amdgcn_readlane(__builtin_bit_cast(int, p0), 63));
            float v1 = __builtin_bit_cast(float, __builtin_amdgcn_readlane(__builtin_bit_cast(int, p1), 63));
            float v2 = __builtin_bit_cast(float, __builtin_amdgcn_readlane(__builtin_bit_cast(int, p2), 63));
            float v3 = __builtin_bit_cast(float, __builtin_amdgcn_readlane(__builtin_bit_cast(int, p3), 63));
            float v4 = __builtin_bit_cast(float, __builtin_amdgcn_readlane(__builtin_bit_cast(int, p4), 63));
            float v5 = __builtin_bit_cast(float, __builtin_amdgcn_readlane(__builtin_bit_cast(int, p5), 63));
            float v6 = __builtin_bit_cast(float, __builtin_amdgcn_readlane(__builtin_bit_cast(int, p6), 63));
            float v7 = __builtin_bit_cast(float, __builtin_amdgcn_readlane(__builtin_bit_cast(int, p7), 63));
            float q0 = fmaf(v1, Ug0[1], v0 * Ug0[0]);
            float q1 = fmaf(v3, Ug0[3], v2 * Ug0[2]);
            float q2 = fmaf(v5, Ug0[5], v4 * Ug0[4]);
            float q3 = fmaf(v7, Ug0[7], v6 * Ug0[6]);
            float av0 = (q0 + q1) + (q2 + q3);
            float s0 = fmaf(v1, Ug1[1], v0 * Ug1[0]);
            float s1 = fmaf(v3, Ug1[3], v2 * Ug1[2]);
            float s2 = fmaf(v5, Ug1[5], v4 * Ug1[4]);
            float s3 = fmaf(v7, Ug1[7], v6 * Ug1[6]);
            float av1 = (s0 + s1) + (s2 + s3);
            ha = fminf(10.0f, fmaxf(-10.0f, fmaf(a0, ha, av0) + xv.x));
            hb = fminf(10.0f, fmaxf(-10.0f, fmaf(a1, hb, av1) + xv.y));
            unsigned hp;
            asm("v_cvt_pk_bf16_f32 %0, %1, %2" : "=v"(hp) : "v"(ha), "v"(hb));
            Hs[i * 68 + lane] = hp;
        }
        short8 Bf[4];
        #pragma unroll
        for (int kc = 0; kc < 4; ++kc)
            Bf[kc] = __builtin_bit_cast(short8,
                *(const uint4*)&Hs[row16 * 68 + kc * 16 + grp * 4]);
        #pragma unroll
        for (int ct = 0; ct < 4; ++ct) {
            f32x4 acc = {0.0f, 0.0f, 0.0f, 0.0f};
            #pragma unroll
            for (int kc = 0; kc < 4; ++kc)
                acc = __builtin_amdgcn_mfma_f32_16x16x32_bf16(Af[ct][kc], Bf[kc], acc, 0, 0, 0);
            #pragma unroll
            for (int r = 0; r < 4; ++r) {
                float y = fminf(10.0f, fmaxf(-10.0f, acc[r]));
                ob[ct][(size_t)r * L_TOT + t16 * 16] = y;
            }
        }
    };

    prefetch(xqA, 0);
    #pragma unroll 1
    for (int t16 = 0; t16 < 32; t16 += 2) {
        prefetch(xqB, t16 + 1);
        do_seg(xqA, t16);
        prefetch(xqA, (t16 + 2) & 31);   // wraps harmlessly on last iter
        do_seg(xqB, t16 + 1);
    }
}

extern "C" void kernel_launch(void* const* d_in, const int* in_sizes, int n_in,
                              void* d_out, int out_size, void* d_ws, size_t ws_size,
                              hipStream_t stream) {
    const float* x          = (const float*)d_in[0];
    const float* g          = (const float*)d_in[1];
    const float* in_proj_w  = (const float*)d_in[2];
    const float* in_proj_b  = (const float*)d_in[3];
    const float* out_proj_w = (const float*)d_in[4];
    const float* U_base     = (const float*)d_in[5];
    const float* V_base     = (const float*)d_in[6];
    const float* a_base     = (const float*)d_in[7];
    const float* mod_uv_w   = (const float*)d_in[8];
    const float* mod_uv_b   = (const float*)d_in[9];
    const float* mod_a_w    = (const float*)d_in[10];
    const float* mod_a_b    = (const float*)d_in[11];
    const float* mod_B_w    = (const float*)d_in[12];
    const float* mod_B_b    = (const float*)d_in[13];
    const float* mod_C_w    = (const float*)d_in[14];
    const float* mod_C_b    = (const float*)d_in[15];
    const float* h0         = (const float*)d_in[16];
    float* out = (float*)d_out;
    float* ws  = (float*)d_ws;
    unsigned* xs16 = (unsigned*)(ws + WS_XS);

    hipLaunchKernelGGL(mod_kernel, dim3(4), dim3(128), 0, stream,
                       g, U_base, V_base, a_base, out_proj_w,
                       mod_uv_w, mod_uv_b, mod_a_w, mod_a_b,
                       mod_B_w, mod_B_b, mod_C_w, mod_C_b, ws);
    hipLaunchKernelGGL(inproj_kernel, dim3(1024, 4), dim3(256), 0, stream,
                       x, in_proj_w, in_proj_b, ws, xs16);
    hipLaunchKernelGGL(scan_kernel, dim3(512), dim3(64), 0, stream,
                       xs16, ws, (const unsigned*)(ws + WS_CGP), h0, out);
}

// Round 13
// 172.095 us; speedup vs baseline: 2.0845x; 1.1142x over previous
//
#include <hip/hip_runtime.h>
#include <hip/hip_fp16.h>

#define L_TOT 65536

// ws float offsets
#define WS_UG   0        // [4][128][8]
#define WS_VG   4096     // [4][128][8]
#define WS_A    8192     // [4][128]
#define WS_GB1  8704     // [4][128]
#define WS_WHP  12288    // uint[128][32]: Wh bf16 pairs (mirror of CgP packing)
#define WS_WLP  16384    // uint[128][32]: Wl residual bf16 pairs
#define WS_CGP  32768    // uint[4][64][64]: packed bf16 pairs of Cg
#define WS_XS   65536    // uint[4][65536][64]: packed fp16 m-pairs of x_seq

typedef __attribute__((ext_vector_type(8))) short short8;
typedef __attribute__((ext_vector_type(4))) float f32x4;

__device__ __forceinline__ unsigned bf16rne(float f) {
    unsigned u = __builtin_bit_cast(unsigned, f);
    return (u + 0x7fffu + ((u >> 16) & 1u)) >> 16;
}
__device__ __forceinline__ float bfhi(unsigned u) {   // bf16 bits (low16) -> float
    return __builtin_bit_cast(float, u << 16);
}

#define DPP_ROW(CT) \
    "v_add_f32_dpp %0, %0, %0 " CT "\n\t" \
    "v_add_f32_dpp %1, %1, %1 " CT "\n\t" \
    "v_add_f32_dpp %2, %2, %2 " CT "\n\t" \
    "v_add_f32_dpp %3, %3, %3 " CT "\n\t" \
    "v_add_f32_dpp %4, %4, %4 " CT "\n\t" \
    "v_add_f32_dpp %5, %5, %5 " CT "\n\t" \
    "v_add_f32_dpp %6, %6, %6 " CT "\n\t" \
    "v_add_f32_dpp %7, %7, %7 " CT "\n\t"

__global__ __launch_bounds__(128) void mod_kernel(
    const float* __restrict__ g, const float* __restrict__ in_proj_w,
    const float* __restrict__ U_base, const float* __restrict__ V_base,
    const float* __restrict__ a_base, const float* __restrict__ out_proj_w,
    const float* __restrict__ mod_uv_w, const float* __restrict__ mod_uv_b,
    const float* __restrict__ mod_a_w, const float* __restrict__ mod_a_b,
    const float* __restrict__ mod_B_w, const float* __restrict__ mod_B_b,
    const float* __restrict__ mod_C_w, const float* __restrict__ mod_C_b,
    float* __restrict__ ws)
{
    __shared__ float gsh[64];
    __shared__ float uvs[16];
    __shared__ float gCs[64];
    const int b = blockIdx.x, tid = threadIdx.x;
    if (tid < 64) gsh[tid] = g[b * 64 + tid];
    __syncthreads();
    if (tid < 16) {
        float s = mod_uv_b[tid];
        for (int d = 0; d < 64; ++d) s += mod_uv_w[tid * 64 + d] * gsh[d];
        uvs[tid] = fminf(0.5f, fmaxf(-0.5f, s));
    }
    float ga_v, gB_v;
    {
        float s = mod_a_b[tid];
        for (int d = 0; d < 64; ++d) s += mod_a_w[tid * 64 + d] * gsh[d];
        ga_v = fminf(2.0f, fmaxf(-2.0f, s));
    }
    {
        float s = mod_B_b[tid];
        for (int d = 0; d < 64; ++d) s += mod_B_w[tid * 64 + d] * gsh[d];
        gB_v = 1.0f + fminf(1.0f, fmaxf(-1.0f, s));
    }
    if (tid < 64) {
        float s = mod_C_b[tid];
        for (int d = 0; d < 64; ++d) s += mod_C_w[tid * 64 + d] * gsh[d];
        gCs[tid] = 1.0f + fminf(0.5f, fmaxf(-0.5f, s));
    }
    __syncthreads();
    for (int idx = tid; idx < 1024; idx += 128) {
        int m = idx >> 3, r = idx & 7;
        ws[WS_UG + (b * 128 + m) * 8 + r] = U_base[m * 8 + r] * (1.0f + uvs[r]);
        ws[WS_VG + (b * 128 + m) * 8 + r] = V_base[m * 8 + r] * (1.0f + uvs[8 + r]);
    }
    ws[WS_A   + b * 128 + tid] = a_base[tid] + ga_v;
    ws[WS_GB1 + b * 128 + tid] = gB_v;
    unsigned* CgP = (unsigned*)(ws + WS_CGP);
    for (int idx = tid; idx < 4096; idx += 128) {
        int c = idx >> 6, j = idx & 63;
        float s = gCs[c];
        float c0 = out_proj_w[c * 128 + 2 * j]     * s;
        float c1 = out_proj_w[c * 128 + 2 * j + 1] * s;
        CgP[(b * 64 + c) * 64 + j] = bf16rne(c0) | (bf16rne(c1) << 16);
    }
    // W packer: textual mirror of the CgP packer above. lo = even k.
    if (b == 0) {
        unsigned* WhP = (unsigned*)(ws + WS_WHP);
        unsigned* WlP = (unsigned*)(ws + WS_WLP);
        for (int idx = tid; idx < 4096; idx += 128) {
            int m = idx >> 5, j = idx & 31;
            float w0 = in_proj_w[m * 64 + 2 * j];
            float w1 = in_proj_w[m * 64 + 2 * j + 1];
            unsigned u0 = bf16rne(w0), u1 = bf16rne(w1);
            WhP[idx] = u0 | (u1 << 16);
            float r0 = w0 - bfhi(u0);
            float r1 = w1 - bfhi(u1);
            WlP[idx] = bf16rne(r0) | (bf16rne(r1) << 16);
        }
    }
}

// MFMA in_proj, full mirror of the proven y-GEMM pattern:
//   A = W (rows m, k=c) from WhP/WlP (packed like CgP);
//   B = X (k=c, cols l) in LDS packed like Hs (row=l, uint=c-pair, stride 36);
//   D rows -> m, cols -> l.  3 chains: Wh Xh + Wh Xl + Wl Xh (~fp32).
__global__ __launch_bounds__(256) void inproj_mfma(
    const float* __restrict__ x, const unsigned* __restrict__ WhP,
    const unsigned* __restrict__ WlP, const float* __restrict__ bias,
    const float* __restrict__ ws, unsigned* __restrict__ xs16)
{
    __shared__ __align__(16) unsigned XhS[64 * 36];
    __shared__ __align__(16) unsigned XlS[64 * 36];
    const int tid = threadIdx.x;
    const int b = blockIdx.y;
    const int l0 = blockIdx.x * 64;

    // stage X transposed-pair-packed: XhS[l*36 + cp] = pk(bf16(x[2cp][l]), bf16(x[2cp+1][l]))
    {
        const int l_st = tid & 63, cpg = tid >> 6;
        #pragma unroll
        for (int s = 0; s < 8; ++s) {
            int cp = cpg * 8 + s;
            float x0 = x[(size_t)(b * 64 + 2 * cp) * L_TOT + l0 + l_st];
            float x1 = x[(size_t)(b * 64 + 2 * cp + 1) * L_TOT + l0 + l_st];
            unsigned u0 = bf16rne(x0), u1 = bf16rne(x1);
            XhS[l_st * 36 + cp] = u0 | (u1 << 16);
            float r0 = x0 - bfhi(u0);
            float r1 = x1 - bfhi(u1);
            XlS[l_st * 36 + cp] = bf16rne(r0) | (bf16rne(r1) << 16);
        }
    }
    const int lane = tid & 63, wv = tid >> 6;
    const int row16 = lane & 15, grp = lane >> 4;

    // A-fragments (mirror of scan's Af read from CgP): wave owns m-tiles 2wv, 2wv+1
    short8 Ah[2][2], Al[2][2];
    #pragma unroll
    for (int t = 0; t < 2; ++t) {
        const int mrow = (2 * wv + t) * 16 + row16;
        #pragma unroll
        for (int kc = 0; kc < 2; ++kc) {
            Ah[t][kc] = __builtin_bit_cast(short8,
                *(const uint4*)(WhP + mrow * 32 + kc * 16 + grp * 4));
            Al[t][kc] = __builtin_bit_cast(short8,
                *(const uint4*)(WlP + mrow * 32 + kc * 16 + grp * 4));
        }
    }
    __syncthreads();

    #pragma unroll
    for (int ti = 0; ti < 4; ++ti) {
        const int lcol = ti * 16 + row16;
        // B-fragments (mirror of scan's Bf read from Hs)
        short8 Bh[2], Bl[2];
        #pragma unroll
        for (int kc = 0; kc < 2; ++kc) {
            Bh[kc] = __builtin_bit_cast(short8,
                *(const uint4*)&XhS[lcol * 36 + kc * 16 + grp * 4]);
            Bl[kc] = __builtin_bit_cast(short8,
                *(const uint4*)&XlS[lcol * 36 + kc * 16 + grp * 4]);
        }
        #pragma unroll
        for (int t = 0; t < 2; ++t) {
            f32x4 acc = {0.f, 0.f, 0.f, 0.f};
            acc = __builtin_amdgcn_mfma_f32_16x16x32_bf16(Ah[t][0], Bh[0], acc, 0, 0, 0);
            acc = __builtin_amdgcn_mfma_f32_16x16x32_bf16(Ah[t][1], Bh[1], acc, 0, 0, 0);
            acc = __builtin_amdgcn_mfma_f32_16x16x32_bf16(Ah[t][0], Bl[0], acc, 0, 0, 0);
            acc = __builtin_amdgcn_mfma_f32_16x16x32_bf16(Ah[t][1], Bl[1], acc, 0, 0, 0);
            acc = __builtin_amdgcn_mfma_f32_16x16x32_bf16(Al[t][0], Bh[0], acc, 0, 0, 0);
            acc = __builtin_amdgcn_mfma_f32_16x16x32_bf16(Al[t][1], Bh[1], acc, 0, 0, 0);
            // D (mirror of scan's ob write): row m = mb + r, col l = lcol
            const int mb = (2 * wv + t) * 16 + 4 * grp;
            const int l = l0 + lcol;
            float4 bi = *(const float4*)(bias + mb);
            float4 gb = *(const float4*)(ws + WS_GB1 + b * 128 + mb);
            float v0 = (acc[0] + bi.x) * gb.x;
            float v1 = (acc[1] + bi.y) * gb.y;
            float v2 = (acc[2] + bi.z) * gb.z;
            float v3 = (acc[3] + bi.w) * gb.w;
            __half2 h01 = __floats2half2_rn(v0, v1);
            __half2 h23 = __floats2half2_rn(v2, v3);
            uint2 pk = {__builtin_bit_cast(unsigned, h01), __builtin_bit_cast(unsigned, h23)};
            *(uint2*)(xs16 + ((size_t)b * L_TOT + l) * 64 + (mb >> 1)) = pk;
        }
    }
}

// One WAVE per (b, chunk). Unchanged from round 11 (passing).
__global__ __launch_bounds__(64, 1) void scan_kernel(
    const unsigned* __restrict__ xs16, const float* __restrict__ ws,
    const unsigned* __restrict__ CgP, const float* __restrict__ h0,
    float* __restrict__ out)
{
    __shared__ __align__(16) unsigned Hs[16 * 68];
    const int lane = threadIdx.x;
    const int bb = blockIdx.x >> 7, k = blockIdx.x & 127;
    const int m0 = 2 * lane;

    float Vg0[8], Vg1[8], Ug0[8], Ug1[8];
    {
        const float* vg = ws + WS_VG + (bb * 128 + m0) * 8;
        const float* ug = ws + WS_UG + (bb * 128 + m0) * 8;
        #pragma unroll
        for (int r = 0; r < 8; ++r) {
            Vg0[r] = vg[r]; Vg1[r] = vg[8 + r];
            Ug0[r] = ug[r]; Ug1[r] = ug[8 + r];
        }
    }
    const float a0 = ws[WS_A + bb * 128 + m0];
    const float a1 = ws[WS_A + bb * 128 + m0 + 1];
    float ha = h0[m0], hb = h0[m0 + 1];

    short8 Af[4][4];
    const int row16 = lane & 15, grp = lane >> 4;
    #pragma unroll
    for (int ct = 0; ct < 4; ++ct)
        #pragma unroll
        for (int kc = 0; kc < 4; ++kc) {
            const unsigned* p = CgP + (bb * 64 + ct * 16 + row16) * 64 + kc * 16 + grp * 4;
            Af[ct][kc] = __builtin_bit_cast(short8, *(const uint4*)p);
        }

    const unsigned* xsp = xs16 + ((size_t)bb * L_TOT + (size_t)k * 512) * 64 + lane;
    float* ob[4];
    #pragma unroll
    for (int ct = 0; ct < 4; ++ct)
        ob[ct] = out + (size_t)(bb * 64 + ct * 16 + grp * 4) * L_TOT + k * 512 + row16;

    unsigned xqA[16], xqB[16];

    auto prefetch = [&](unsigned (&xq)[16], int seg) {
        const unsigned* xb = xsp + (size_t)seg * 1024;
        #pragma unroll
        for (int i = 0; i < 16; ++i) xq[i] = xb[(size_t)i * 64];
    };
    auto do_seg = [&](const unsigned (&xq)[16], int t16) {
        #pragma unroll
        for (int i = 0; i < 16; ++i) {
            const float2 xv = __half22float2(__builtin_bit_cast(__half2, xq[i]));
            float p0 = fmaf(Vg1[0], hb, Vg0[0] * ha);
            float p1 = fmaf(Vg1[1], hb, Vg0[1] * ha);
            float p2 = fmaf(Vg1[2], hb, Vg0[2] * ha);
            float p3 = fmaf(Vg1[3], hb, Vg0[3] * ha);
            float p4 = fmaf(Vg1[4], hb, Vg0[4] * ha);
            float p5 = fmaf(Vg1[5], hb, Vg0[5] * ha);
            float p6 = fmaf(Vg1[6], hb, Vg0[6] * ha);
            float p7 = fmaf(Vg1[7], hb, Vg0[7] * ha);
            asm volatile(
                "s_nop 1\n\t"
                DPP_ROW("quad_perm:[1,0,3,2] row_mask:0xf bank_mask:0xf bound_ctrl:1")
                DPP_ROW("quad_perm:[2,3,0,1] row_mask:0xf bank_mask:0xf bound_ctrl:1")
                DPP_ROW("row_half_mirror row_mask:0xf bank_mask:0xf bound_ctrl:1")
                DPP_ROW("row_mirror row_mask:0xf bank_mask:0xf bound_ctrl:1")
                DPP_ROW("row_bcast:15 row_mask:0xa bank_mask:0xf")
                DPP_ROW("row_bcast:31 row_mask:0xc bank_mask:0xf")
                : "+v"(p0), "+v"(p1), "+v"(p2), "+v"(p3),
                  "+v"(p4), "+v"(p5), "+v"(p6), "+v"(p7));
            float v0 = __builtin_bit_cast(float, __builtin_amdgcn_readlane(__builtin_bit_cast(int, p0), 63));
            float v1 = __builtin_bit_cast(float, __builtin_amdgcn_readlane(__builtin_bit_cast(int, p1), 63));
            float v2 = __builtin_bit_cast(float, __builtin_amdgcn_readlane(__builtin_bit_cast(int, p2), 63));
            float v3 = __builtin_bit_cast(float, __builtin_amdgcn_readlane(__builtin_bit_cast(int, p3), 63));
            float v4 = __builtin_bit_cast(float, __builtin_amdgcn_readlane(__builtin_bit_cast(int, p4), 63));
            float v5 = __builtin_bit_cast(float, __builtin_amdgcn_readlane(__builtin_bit_cast(int, p5), 63));
            float v6 = __builtin_bit_cast(float, __builtin_amdgcn_readlane(__builtin_bit_cast(int, p6), 63));
            float v7 = __builtin_bit_cast(float, __builtin_amdgcn_readlane(__builtin_bit_cast(int, p7), 63));
            float q0 = fmaf(v1, Ug0[1], v0 * Ug0[0]);
            float q1 = fmaf(v3, Ug0[3], v2 * Ug0[2]);
            float q2 = fmaf(v5, Ug0[5], v4 * Ug0[4]);
            float q3 = fmaf(v7, Ug0[7], v6 * Ug0[6]);
            float av0 = (q0 + q1) + (q2 + q3);
            float s0 = fmaf(v1, Ug1[1], v0 * Ug1[0]);
            float s1 = fmaf(v3, Ug1[3], v2 * Ug1[2]);
            float s2 = fmaf(v5, Ug1[5], v4 * Ug1[4]);
            float s3 = fmaf(v7, Ug1[7], v6 * Ug1[6]);
            float av1 = (s0 + s1) + (s2 + s3);
            ha = fminf(10.0f, fmaxf(-10.0f, fmaf(a0, ha, av0) + xv.x));
            hb = fminf(10.0f, fmaxf(-10.0f, fmaf(a1, hb, av1) + xv.y));
            unsigned hp;
            asm("v_cvt_pk_bf16_f32 %0, %1, %2" : "=v"(hp) : "v"(ha), "v"(hb));
            Hs[i * 68 + lane] = hp;
        }
        short8 Bf[4];
        #pragma unroll
        for (int kc = 0; kc < 4; ++kc)
            Bf[kc] = __builtin_bit_cast(short8,
                *(const uint4*)&Hs[row16 * 68 + kc * 16 + grp * 4]);
        #pragma unroll
        for (int ct = 0; ct < 4; ++ct) {
            f32x4 acc = {0.0f, 0.0f, 0.0f, 0.0f};
            #pragma unroll
            for (int kc = 0; kc < 4; ++kc)
                acc = __builtin_amdgcn_mfma_f32_16x16x32_bf16(Af[ct][kc], Bf[kc], acc, 0, 0, 0);
            #pragma unroll
            for (int r = 0; r < 4; ++r) {
                float y = fminf(10.0f, fmaxf(-10.0f, acc[r]));
                ob[ct][(size_t)r * L_TOT + t16 * 16] = y;
            }
        }
    };

    prefetch(xqA, 0);
    #pragma unroll 1
    for (int t16 = 0; t16 < 32; t16 += 2) {
        prefetch(xqB, t16 + 1);
        do_seg(xqA, t16);
        prefetch(xqA, (t16 + 2) & 31);
        do_seg(xqB, t16 + 1);
    }
}

extern "C" void kernel_launch(void* const* d_in, const int* in_sizes, int n_in,
                              void* d_out, int out_size, void* d_ws, size_t ws_size,
                              hipStream_t stream) {
    const float* x          = (const float*)d_in[0];
    const float* g          = (const float*)d_in[1];
    const float* in_proj_w  = (const float*)d_in[2];
    const float* in_proj_b  = (const float*)d_in[3];
    const float* out_proj_w = (const float*)d_in[4];
    const float* U_base     = (const float*)d_in[5];
    const float* V_base     = (const float*)d_in[6];
    const float* a_base     = (const float*)d_in[7];
    const float* mod_uv_w   = (const float*)d_in[8];
    const float* mod_uv_b   = (const float*)d_in[9];
    const float* mod_a_w    = (const float*)d_in[10];
    const float* mod_a_b    = (const float*)d_in[11];
    const float* mod_B_w    = (const float*)d_in[12];
    const float* mod_B_b    = (const float*)d_in[13];
    const float* mod_C_w    = (const float*)d_in[14];
    const float* mod_C_b    = (const float*)d_in[15];
    const float* h0         = (const float*)d_in[16];
    float* out = (float*)d_out;
    float* ws  = (float*)d_ws;
    unsigned* xs16 = (unsigned*)(ws + WS_XS);

    hipLaunchKernelGGL(mod_kernel, dim3(4), dim3(128), 0, stream,
                       g, in_proj_w, U_base, V_base, a_base, out_proj_w,
                       mod_uv_w, mod_uv_b, mod_a_w, mod_a_b,
                       mod_B_w, mod_B_b, mod_C_w, mod_C_b, ws);
    hipLaunchKernelGGL(inproj_mfma, dim3(1024, 4), dim3(256), 0, stream,
                       x, (const unsigned*)(ws + WS_WHP), (const unsigned*)(ws + WS_WLP),
                       in_proj_b, ws, xs16);
    hipLaunchKernelGGL(scan_kernel, dim3(512), dim3(64), 0, stream,
                       xs16, ws, (const unsigned*)(ws + WS_CGP), h0, out);
}